// Round 9
// baseline (99.008 us; speedup 1.0000x reference)
//
#include <hip/hip_runtime.h>
#include <math.h>

// ---------------------------------------------------------------------------
// CAGPool layer, MI355X. Outputs concatenated flat as float32 values:
//   [0]      : x_out          [B*k, D]
//   [o1]     : edge_index_new [2, E]  (ids as floats, -1 for dropped)
//   [o2]     : batch_out      [B*k]
//   [o3]     : perm           [B*k]
//   [o4]     : valid          [E]   (0.0 / 1.0)
//
// MEASUREMENT ROUND: gather_out and edge_out run REPS=2 (idempotent repeats)
// so dur_us = base + gather_real + edge_real, and doubled phases surface in
// rocprof top-5 with counters. Ordering logic unchanged from passing rounds.
// ---------------------------------------------------------------------------

typedef float  nfloat4 __attribute__((ext_vector_type(4)));
typedef int    nint4   __attribute__((ext_vector_type(4)));

__device__ __forceinline__ void nt_store4(float4* p, float4 v) {
    nfloat4 nv = { v.x, v.y, v.z, v.w };
    __builtin_nontemporal_store(nv, reinterpret_cast<nfloat4*>(p));
}
__device__ __forceinline__ int4 nt_load4(const int4* p) {
    nint4 nv = __builtin_nontemporal_load(reinterpret_cast<const nint4*>(p));
    int4 r; r.x = nv.x; r.y = nv.y; r.z = nv.z; r.w = nv.w;
    return r;
}

__global__ __launch_bounds__(256)
void score_hi_kernel(const float4* __restrict__ x4,
                     const float4* __restrict__ pool4,
                     double* __restrict__ scores, int n) {
    const int w = threadIdx.x >> 6, l = threadIdx.x & 63;
    const int row = blockIdx.x * 16 + w * 4;      // 4 rows per wave
    const int b = row / n;                        // n%16==0 -> uniform per block

    float4 pv = pool4[(size_t)b * 64 + l];        // D=256: one float4 per lane
    double px = pv.x, py = pv.y, pz = pv.z, pw = pv.w;
    double nn = px * px + py * py + pz * pz + pw * pw;
    for (int off = 32; off > 0; off >>= 1) nn += __shfl_xor(nn, off, 64);
    double inv = 1.0 / sqrt(nn);

    const float4* xa = x4 + (size_t)row * 64;
    float4 va = xa[l], vb = xa[64 + l], vc = xa[128 + l], vd = xa[192 + l];
    double da = (double)va.x * px + (double)va.y * py
              + (double)va.z * pz + (double)va.w * pw;
    double db = (double)vb.x * px + (double)vb.y * py
              + (double)vb.z * pz + (double)vb.w * pw;
    double dc = (double)vc.x * px + (double)vc.y * py
              + (double)vc.z * pz + (double)vc.w * pw;
    double dd = (double)vd.x * px + (double)vd.y * py
              + (double)vd.z * pz + (double)vd.w * pw;
    for (int off = 32; off > 0; off >>= 1) {      // 4 independent chains
        da += __shfl_xor(da, off, 64);
        db += __shfl_xor(db, off, 64);
        dc += __shfl_xor(dc, off, 64);
        dd += __shfl_xor(dd, off, 64);
    }
    if (l == 0) {
        scores[row]     = da * inv;
        scores[row + 1] = db * inv;
        scores[row + 2] = dc * inv;
        scores[row + 3] = dd * inv;
    }
}

// --- K2: exact top-k rank per graph; emits nodemap/perm/gate/batch ----------
__global__ void rank_gate_kernel(const double* __restrict__ scores,
                                 int* __restrict__ nodemap,
                                 int* __restrict__ perm_int,
                                 float* __restrict__ gate,
                                 float* __restrict__ out,
                                 long off_batch, long off_perm,
                                 int n, int k) {
    extern __shared__ double s[];
    int b = blockIdx.x;
    int t = threadIdx.x;                  // block = n threads
    int gid = b * n + t;
    double st = scores[gid];
    s[t] = st;
    __syncthreads();
    int rank = 0;
#pragma unroll 8
    for (int j = 0; j < n; ++j) {
        double sj = s[j];
        rank += (int)((sj > st) || (sj == st && j < t));
    }
    if (rank < k) {
        int p = b * k + rank;
        nodemap[gid] = p;
        perm_int[p] = gid;
        gate[p] = (float)(1.0 / (1.0 + exp(-st)));
        out[off_batch + p] = (float)b;
        out[off_perm + p]  = (float)gid;
    } else {
        nodemap[gid] = -1;
    }
}

// --- K3a: gather x_out, 16 rows/block, 4 rows/wave, REPS repeats ------------
__global__ __launch_bounds__(256)
void gather_out_kernel(const float4* __restrict__ x4,
                       const float* __restrict__ gate,
                       const int* __restrict__ perm_int,
                       float4* __restrict__ out0, int reps) {
    int w = threadIdx.x >> 6, l = threadIdx.x & 63;
    int p0 = blockIdx.x * 16 + w * 4;
    for (int r = 0; r < reps; ++r) {
        int g0 = perm_int[p0],     g1 = perm_int[p0 + 1];
        int g2 = perm_int[p0 + 2], g3 = perm_int[p0 + 3];
        float f0 = gate[p0],     f1 = gate[p0 + 1];
        float f2 = gate[p0 + 2], f3 = gate[p0 + 3];
        float4 v0 = x4[(size_t)g0 * 64 + l];
        float4 v1 = x4[(size_t)g1 * 64 + l];
        float4 v2 = x4[(size_t)g2 * 64 + l];
        float4 v3 = x4[(size_t)g3 * 64 + l];
        v0.x *= f0; v0.y *= f0; v0.z *= f0; v0.w *= f0;
        v1.x *= f1; v1.y *= f1; v1.z *= f1; v1.w *= f1;
        v2.x *= f2; v2.y *= f2; v2.z *= f2; v2.w *= f2;
        v3.x *= f3; v3.y *= f3; v3.z *= f3; v3.w *= f3;
        nt_store4(&out0[(size_t)(p0    ) * 64 + l], v0);
        nt_store4(&out0[(size_t)(p0 + 1) * 64 + l], v1);
        nt_store4(&out0[(size_t)(p0 + 2) * 64 + l], v2);
        nt_store4(&out0[(size_t)(p0 + 3) * 64 + l], v3);
        asm volatile("" ::: "memory");   // keep rep-2 loads/stores real
    }
}

// --- K3b: edge remap + validity, 2048 edges/block, REPS repeats -------------
__global__ __launch_bounds__(256)
void edge_out_kernel(const int4* __restrict__ ei_src,
                     const int4* __restrict__ ei_dst,
                     const int* __restrict__ nodemap,
                     float4* __restrict__ out_row,
                     float4* __restrict__ out_col,
                     float4* __restrict__ out_valid,
                     long epg4, int n, int reps) {
    __shared__ int smem[1024];
    long e4base = (long)blockIdx.x * 512;         // int4 units -> 2048 edges
    long g = e4base / epg4;
    int base = (int)(g * (long)n);
    long e0 = e4base + threadIdx.x;
    long e1 = e0 + 256;
    for (int r = 0; r < reps; ++r) {
        __syncthreads();
        int4 s0 = nt_load4(&ei_src[e0]);
        int4 s1 = nt_load4(&ei_src[e1]);
        int4 d0 = nt_load4(&ei_dst[e0]);
        int4 d1 = nt_load4(&ei_dst[e1]);
        for (int i = threadIdx.x; i < n; i += 256)
            smem[i] = nodemap[base + i];
        __syncthreads();

        int r0 = smem[s0.x - base], r1 = smem[s0.y - base];
        int r2 = smem[s0.z - base], r3 = smem[s0.w - base];
        int c0 = smem[d0.x - base], c1 = smem[d0.y - base];
        int c2 = smem[d0.z - base], c3 = smem[d0.w - base];
        bool v0 = (r0 >= 0) & (c0 >= 0);
        bool v1 = (r1 >= 0) & (c1 >= 0);
        bool v2 = (r2 >= 0) & (c2 >= 0);
        bool v3 = (r3 >= 0) & (c3 >= 0);
        float4 rv = { v0 ? (float)r0 : -1.0f, v1 ? (float)r1 : -1.0f,
                      v2 ? (float)r2 : -1.0f, v3 ? (float)r3 : -1.0f };
        float4 cv = { v0 ? (float)c0 : -1.0f, v1 ? (float)c1 : -1.0f,
                      v2 ? (float)c2 : -1.0f, v3 ? (float)c3 : -1.0f };
        float4 vv = { v0 ? 1.0f : 0.0f, v1 ? 1.0f : 0.0f,
                      v2 ? 1.0f : 0.0f, v3 ? 1.0f : 0.0f };
        nt_store4(&out_row[e0], rv);
        nt_store4(&out_col[e0], cv);
        nt_store4(&out_valid[e0], vv);

        int q0 = smem[s1.x - base], q1 = smem[s1.y - base];
        int q2 = smem[s1.z - base], q3 = smem[s1.w - base];
        int u0 = smem[d1.x - base], u1 = smem[d1.y - base];
        int u2 = smem[d1.z - base], u3 = smem[d1.w - base];
        bool w0 = (q0 >= 0) & (u0 >= 0);
        bool w1 = (q1 >= 0) & (u1 >= 0);
        bool w2 = (q2 >= 0) & (u2 >= 0);
        bool w3 = (q3 >= 0) & (u3 >= 0);
        float4 rv1 = { w0 ? (float)q0 : -1.0f, w1 ? (float)q1 : -1.0f,
                       w2 ? (float)q2 : -1.0f, w3 ? (float)q3 : -1.0f };
        float4 cv1 = { w0 ? (float)u0 : -1.0f, w1 ? (float)u1 : -1.0f,
                       w2 ? (float)u2 : -1.0f, w3 ? (float)u3 : -1.0f };
        float4 vv1 = { w0 ? 1.0f : 0.0f, w1 ? 1.0f : 0.0f,
                       w2 ? 1.0f : 0.0f, w3 ? 1.0f : 0.0f };
        nt_store4(&out_row[e1], rv1);
        nt_store4(&out_col[e1], cv1);
        nt_store4(&out_valid[e1], vv1);
        asm volatile("" ::: "memory");
    }
}

// ======================= fallback path (general sizes) ======================
__global__ void norm_kernel(const float* __restrict__ pool,
                            double* __restrict__ inv_norm, int D) {
    int b = blockIdx.x;
    int l = threadIdx.x;
    double acc = 0.0;
    for (int j = l; j < D; j += 64) {
        double v = (double)pool[(size_t)b * D + j];
        acc += v * v;
    }
    for (int off = 32; off > 0; off >>= 1) acc += __shfl_down(acc, off, 64);
    if (l == 0) inv_norm[b] = 1.0 / sqrt(acc);
}

__global__ void score_kernel(const float* __restrict__ x,
                             const float* __restrict__ pool,
                             const double* __restrict__ inv_norm,
                             double* __restrict__ scores,
                             int D, int n) {
    int node = blockIdx.x * 4 + (threadIdx.x >> 6);
    int l = threadIdx.x & 63;
    int b = node / n;
    const float* xr = x + (size_t)node * D;
    const float* pr = pool + (size_t)b * D;
    double acc = 0.0;
    for (int j = l; j < D; j += 64)
        acc += (double)xr[j] * (double)pr[j];
    for (int off = 32; off > 0; off >>= 1) acc += __shfl_down(acc, off, 64);
    if (l == 0) scores[node] = acc * inv_norm[b];
}

__global__ void rank_kernel(const double* __restrict__ scores,
                            int* __restrict__ nodemap,
                            int* __restrict__ perm_int,
                            float* __restrict__ out,
                            long off_batch, long off_perm,
                            int n, int k) {
    extern __shared__ double sdyn[];
    int b = blockIdx.x;
    int t = threadIdx.x;
    int gid = b * n + t;
    double st = scores[gid];
    sdyn[t] = st;
    __syncthreads();
    int rank = 0;
    for (int j = 0; j < n; ++j) {
        double sj = sdyn[j];
        rank += (int)((sj > st) || (sj == st && j < t));
    }
    if (rank < k) {
        int p = b * k + rank;
        nodemap[gid] = p;
        perm_int[p] = gid;
        out[off_batch + p] = (float)b;
        out[off_perm + p]  = (float)gid;
    } else {
        nodemap[gid] = -1;
    }
}

__global__ void gather_kernel(const float* __restrict__ x,
                              const double* __restrict__ scores,
                              const int* __restrict__ perm_int,
                              float* __restrict__ out0, int D) {
    int p = blockIdx.x;
    int l = threadIdx.x;
    int gid = perm_int[p];
    double sc = scores[gid];
    float g = (float)(1.0 / (1.0 + exp(-sc)));
    const float* xr = x + (size_t)gid * D;
    float* orow = out0 + (size_t)p * D;
    for (int j = l; j < D; j += 64) orow[j] = xr[j] * g;
}

__global__ void edge_kernel(const int* __restrict__ ei,
                            const int* __restrict__ nodemap,
                            float* __restrict__ out,
                            long off_e, long off_valid, long E) {
    long e = (long)blockIdx.x * blockDim.x + threadIdx.x;
    if (e >= E) return;
    int r = nodemap[ei[e]];
    int c = nodemap[ei[E + e]];
    bool valid = (r >= 0) && (c >= 0);
    out[off_e + e]     = valid ? (float)r : -1.0f;
    out[off_e + E + e] = valid ? (float)c : -1.0f;
    out[off_valid + e] = valid ? 1.0f : 0.0f;
}

// ============================================================================
extern "C" void kernel_launch(void* const* d_in, const int* in_sizes, int n_in,
                              void* d_out, int out_size, void* d_ws, size_t ws_size,
                              hipStream_t stream) {
    const float* x    = (const float*)d_in[0];
    const int*   ei   = (const int*)d_in[1];
    const float* pool = (const float*)d_in[3];

    const int B = in_sizes[4];
    const int D = in_sizes[3] / B;
    const long N = (long)in_sizes[0] / D;
    const long E = (long)in_sizes[1] / 2;
    const int n = (int)(N / B);
    const int k = (n + 1) / 2;            // ceil(0.5 * n)
    const long Eg = E / B;                // edges per graph

    // workspace layout
    char* ws = (char*)d_ws;
    double* scores   = (double*)ws;                 ws += (size_t)N * 8;
    double* inv_norm = (double*)ws;                 ws += (size_t)B * 8;
    int*    nodemap  = (int*)ws;                    ws += (size_t)N * 4;
    int*    perm_int = (int*)ws;                    ws += (size_t)B * ((size_t)(n + 1) / 2) * 4;
    float*  gate     = (float*)ws;

    float* out = (float*)d_out;
    const long o0 = 0;                       // x_out [B*k, D]
    const long o1 = o0 + (long)B * k * D;    // edge_index_new [2, E]
    const long o2 = o1 + 2 * E;              // batch_out [B*k]
    const long o3 = o2 + (long)B * k;        // perm [B*k]
    const long o4 = o3 + (long)B * k;        // valid [E]

    bool fast_ok = (D == 256) && (n % 16 == 0) && (n <= 1024) &&
                   ((long)B * k % 16 == 0) &&
                   (E % 2048 == 0) && (Eg % 2048 == 0) &&
                   (o1 % 4 == 0) && ((o1 + E) % 4 == 0) && (o4 % 4 == 0);

    if (fast_ok) {
        const int REPS = 2;   // measurement: double gather/edge phases
        score_hi_kernel<<<(int)(N / 16), 256, 0, stream>>>(
            (const float4*)x, (const float4*)pool, scores, n);
        rank_gate_kernel<<<B, n, (size_t)n * sizeof(double), stream>>>(
            scores, nodemap, perm_int, gate, out, o2, o3, n, k);
        int GA = (int)((long)B * k / 16);
        int GB = (int)(E / 2048);
        gather_out_kernel<<<GA, 256, 0, stream>>>(
            (const float4*)x, gate, perm_int, (float4*)(out + o0), REPS);
        edge_out_kernel<<<GB, 256, 0, stream>>>(
            (const int4*)ei, (const int4*)(ei + E), nodemap,
            (float4*)(out + o1), (float4*)(out + o1 + E), (float4*)(out + o4),
            Eg / 4, n, REPS);
    } else {
        norm_kernel<<<B, 64, 0, stream>>>(pool, inv_norm, D);
        score_kernel<<<(int)(N / 4), 256, 0, stream>>>(
            x, pool, inv_norm, scores, D, n);
        rank_kernel<<<B, n, (size_t)n * sizeof(double), stream>>>(
            scores, nodemap, perm_int, out, o2, o3, n, k);
        gather_kernel<<<(int)((long)B * k), 64, 0, stream>>>(
            x, scores, perm_int, out + o0, D);
        edge_kernel<<<(int)((E + 255) / 256), 256, 0, stream>>>(
            ei, nodemap, out, o1, o4, E);
    }
}

// Round 10
// 79.010 us; speedup vs baseline: 1.2531x; 1.2531x over previous
//
#include <hip/hip_runtime.h>
#include <math.h>

// ---------------------------------------------------------------------------
// CAGPool layer, MI355X. Outputs concatenated flat as float32 values:
//   [0]      : x_out          [B*k, D]
//   [o1]     : edge_index_new [2, E]  (ids as floats, -1 for dropped)
//   [o2]     : batch_out      [B*k]
//   [o3]     : perm           [B*k]
//   [o4]     : valid          [E]   (0.0 / 1.0)
//
// Ordering must match jax.lax.top_k exactly. Scores in float64, bit-identical
// per-row summation structure across all passing rounds.
//
// Fast path (R9 theory: kill the 67MB x re-read):
//   K1 score+rank+GATHER fused, one 1024-thread block per graph. Gather runs
//      right after rank (only ~4us of zero-traffic compute since this block
//      streamed its graph's x), so x rows are L2/L3-hot.
//   K2 edges: high-occupancy (2048 blocks), LDS nodemap, NT loads/stores.
// ---------------------------------------------------------------------------

typedef float  nfloat4 __attribute__((ext_vector_type(4)));
typedef int    nint4   __attribute__((ext_vector_type(4)));

__device__ __forceinline__ void nt_store4(float4* p, float4 v) {
    nfloat4 nv = { v.x, v.y, v.z, v.w };
    __builtin_nontemporal_store(nv, reinterpret_cast<nfloat4*>(p));
}
__device__ __forceinline__ int4 nt_load4(const int4* p) {
    nint4 nv = __builtin_nontemporal_load(reinterpret_cast<const nint4*>(p));
    int4 r; r.x = nv.x; r.y = nv.y; r.z = nv.z; r.w = nv.w;
    return r;
}

// --- K1: score + rank + gather, one block per graph -------------------------
__global__ __launch_bounds__(1024)
void srg_kernel(const float4* __restrict__ x4,
                const float4* __restrict__ pool4,
                int* __restrict__ nodemap,          // global, for edge kernel
                float4* __restrict__ out0,
                float* __restrict__ out_batch,
                float* __restrict__ out_perm,
                int n, int k) {
    __shared__ double s[1024];
    __shared__ int    perm_l[512];
    __shared__ float  gate_l[512];

    const int b = blockIdx.x;
    const int t = threadIdx.x;
    const int w = t >> 6, l = t & 63;
    const int nw = blockDim.x >> 6;     // 16 waves

    // ---- phase 1: scores (bit-identical structure to passing rounds) ------
    float4 pv = pool4[(size_t)b * 64 + l];      // D=256: one float4 per lane
    double px = pv.x, py = pv.y, pz = pv.z, pw = pv.w;
    double nn = px * px + py * py + pz * pz + pw * pw;
    for (int off = 32; off > 0; off >>= 1) nn += __shfl_xor(nn, off, 64);
    double inv = 1.0 / sqrt(nn);

    const int npw = n / nw;             // nodes per wave (multiple of 4)
    const float4* xg = x4 + ((size_t)b * n + (size_t)w * npw) * 64;

    float4 va = xg[l], vb = xg[64 + l], vc = xg[128 + l], vd = xg[192 + l];
    for (int i = 0; i < npw; i += 4) {
        float4 na, nb, nc, nd;
        bool more = (i + 4 < npw);
        if (more) {                      // prefetch next 4 rows
            const float4* xn = xg + (size_t)(i + 4) * 64;
            na = xn[l]; nb = xn[64 + l]; nc = xn[128 + l]; nd = xn[192 + l];
        }
        double da = (double)va.x * px + (double)va.y * py
                  + (double)va.z * pz + (double)va.w * pw;
        double db = (double)vb.x * px + (double)vb.y * py
                  + (double)vb.z * pz + (double)vb.w * pw;
        double dc = (double)vc.x * px + (double)vc.y * py
                  + (double)vc.z * pz + (double)vc.w * pw;
        double dd = (double)vd.x * px + (double)vd.y * py
                  + (double)vd.z * pz + (double)vd.w * pw;
        for (int off = 32; off > 0; off >>= 1) {   // 4 independent chains
            da += __shfl_xor(da, off, 64);
            db += __shfl_xor(db, off, 64);
            dc += __shfl_xor(dc, off, 64);
            dd += __shfl_xor(dd, off, 64);
        }
        if (l == 0) {
            int base = w * npw + i;
            s[base]     = da * inv;
            s[base + 1] = db * inv;
            s[base + 2] = dc * inv;
            s[base + 3] = dd * inv;
        }
        if (more) { va = na; vb = nb; vc = nc; vd = nd; }
    }
    __syncthreads();

    // ---- phase 2: exact top-k rank -----------------------------------------
    if (t < n) {
        double st = s[t];
        int rank = 0;
#pragma unroll 8
        for (int j = 0; j < n; ++j) {
            double sj = s[j];
            rank += (int)((sj > st) || (sj == st && j < t));
        }
        if (rank < k) {
            int p = b * k + rank;
            nodemap[b * n + t] = p;
            perm_l[rank] = t;
            gate_l[rank] = (float)(1.0 / (1.0 + exp(-st)));
            out_batch[p] = (float)b;
            out_perm[p]  = (float)(b * n + t);
        } else {
            nodemap[b * n + t] = -1;
        }
    }
    __syncthreads();

    // ---- phase 3: gather x_out (x rows L2/L3-hot; only rank in between) ----
    {
        const size_t xbase = (size_t)b * n * 64;
        const size_t obase = (size_t)b * k * 64;
        const int rpw = k / 16;                 // rows per wave (k%64==0 -> %4==0)
        const int rbase = w * rpw;
        for (int i = 0; i < rpw; i += 4) {
            int r0 = rbase + i;
            int g0 = perm_l[r0],     g1 = perm_l[r0 + 1];
            int g2 = perm_l[r0 + 2], g3 = perm_l[r0 + 3];
            float f0 = gate_l[r0],     f1 = gate_l[r0 + 1];
            float f2 = gate_l[r0 + 2], f3 = gate_l[r0 + 3];
            float4 v0 = x4[xbase + (size_t)g0 * 64 + l];
            float4 v1 = x4[xbase + (size_t)g1 * 64 + l];
            float4 v2 = x4[xbase + (size_t)g2 * 64 + l];
            float4 v3 = x4[xbase + (size_t)g3 * 64 + l];
            v0.x *= f0; v0.y *= f0; v0.z *= f0; v0.w *= f0;
            v1.x *= f1; v1.y *= f1; v1.z *= f1; v1.w *= f1;
            v2.x *= f2; v2.y *= f2; v2.z *= f2; v2.w *= f2;
            v3.x *= f3; v3.y *= f3; v3.z *= f3; v3.w *= f3;
            nt_store4(&out0[obase + (size_t)(r0    ) * 64 + l], v0);
            nt_store4(&out0[obase + (size_t)(r0 + 1) * 64 + l], v1);
            nt_store4(&out0[obase + (size_t)(r0 + 2) * 64 + l], v2);
            nt_store4(&out0[obase + (size_t)(r0 + 3) * 64 + l], v3);
        }
    }
}

// --- K2: edge remap + validity, 2048 edges/block ----------------------------
__global__ __launch_bounds__(256)
void edge_out_kernel(const int4* __restrict__ ei_src,
                     const int4* __restrict__ ei_dst,
                     const int* __restrict__ nodemap,
                     float4* __restrict__ out_row,
                     float4* __restrict__ out_col,
                     float4* __restrict__ out_valid,
                     long epg4, int n) {
    __shared__ int smem[1024];
    long e4base = (long)blockIdx.x * 512;         // int4 units -> 2048 edges
    long g = e4base / epg4;
    int base = (int)(g * (long)n);
    long e0 = e4base + threadIdx.x;
    long e1 = e0 + 256;
    int4 s0 = nt_load4(&ei_src[e0]);
    int4 s1 = nt_load4(&ei_src[e1]);
    int4 d0 = nt_load4(&ei_dst[e0]);
    int4 d1 = nt_load4(&ei_dst[e1]);
    for (int i = threadIdx.x; i < n; i += 256)
        smem[i] = nodemap[base + i];
    __syncthreads();

    int r0 = smem[s0.x - base], r1 = smem[s0.y - base];
    int r2 = smem[s0.z - base], r3 = smem[s0.w - base];
    int c0 = smem[d0.x - base], c1 = smem[d0.y - base];
    int c2 = smem[d0.z - base], c3 = smem[d0.w - base];
    bool v0 = (r0 >= 0) & (c0 >= 0);
    bool v1 = (r1 >= 0) & (c1 >= 0);
    bool v2 = (r2 >= 0) & (c2 >= 0);
    bool v3 = (r3 >= 0) & (c3 >= 0);
    float4 rv = { v0 ? (float)r0 : -1.0f, v1 ? (float)r1 : -1.0f,
                  v2 ? (float)r2 : -1.0f, v3 ? (float)r3 : -1.0f };
    float4 cv = { v0 ? (float)c0 : -1.0f, v1 ? (float)c1 : -1.0f,
                  v2 ? (float)c2 : -1.0f, v3 ? (float)c3 : -1.0f };
    float4 vv = { v0 ? 1.0f : 0.0f, v1 ? 1.0f : 0.0f,
                  v2 ? 1.0f : 0.0f, v3 ? 1.0f : 0.0f };
    nt_store4(&out_row[e0], rv);
    nt_store4(&out_col[e0], cv);
    nt_store4(&out_valid[e0], vv);

    int q0 = smem[s1.x - base], q1 = smem[s1.y - base];
    int q2 = smem[s1.z - base], q3 = smem[s1.w - base];
    int u0 = smem[d1.x - base], u1 = smem[d1.y - base];
    int u2 = smem[d1.z - base], u3 = smem[d1.w - base];
    bool w0 = (q0 >= 0) & (u0 >= 0);
    bool w1 = (q1 >= 0) & (u1 >= 0);
    bool w2 = (q2 >= 0) & (u2 >= 0);
    bool w3 = (q3 >= 0) & (u3 >= 0);
    float4 rv1 = { w0 ? (float)q0 : -1.0f, w1 ? (float)q1 : -1.0f,
                   w2 ? (float)q2 : -1.0f, w3 ? (float)q3 : -1.0f };
    float4 cv1 = { w0 ? (float)u0 : -1.0f, w1 ? (float)u1 : -1.0f,
                   w2 ? (float)u2 : -1.0f, w3 ? (float)u3 : -1.0f };
    float4 vv1 = { w0 ? 1.0f : 0.0f, w1 ? 1.0f : 0.0f,
                   w2 ? 1.0f : 0.0f, w3 ? 1.0f : 0.0f };
    nt_store4(&out_row[e1], rv1);
    nt_store4(&out_col[e1], cv1);
    nt_store4(&out_valid[e1], vv1);
}

// ======================= fallback path (general sizes) ======================
__global__ void norm_kernel(const float* __restrict__ pool,
                            double* __restrict__ inv_norm, int D) {
    int b = blockIdx.x;
    int l = threadIdx.x;
    double acc = 0.0;
    for (int j = l; j < D; j += 64) {
        double v = (double)pool[(size_t)b * D + j];
        acc += v * v;
    }
    for (int off = 32; off > 0; off >>= 1) acc += __shfl_down(acc, off, 64);
    if (l == 0) inv_norm[b] = 1.0 / sqrt(acc);
}

__global__ void score_kernel(const float* __restrict__ x,
                             const float* __restrict__ pool,
                             const double* __restrict__ inv_norm,
                             double* __restrict__ scores,
                             int D, int n) {
    int node = blockIdx.x * 4 + (threadIdx.x >> 6);
    int l = threadIdx.x & 63;
    int b = node / n;
    const float* xr = x + (size_t)node * D;
    const float* pr = pool + (size_t)b * D;
    double acc = 0.0;
    for (int j = l; j < D; j += 64)
        acc += (double)xr[j] * (double)pr[j];
    for (int off = 32; off > 0; off >>= 1) acc += __shfl_down(acc, off, 64);
    if (l == 0) scores[node] = acc * inv_norm[b];
}

__global__ void rank_kernel(const double* __restrict__ scores,
                            int* __restrict__ nodemap,
                            int* __restrict__ perm_int,
                            float* __restrict__ out,
                            long off_batch, long off_perm,
                            int n, int k) {
    extern __shared__ double sdyn[];
    int b = blockIdx.x;
    int t = threadIdx.x;
    int gid = b * n + t;
    double st = scores[gid];
    sdyn[t] = st;
    __syncthreads();
    int rank = 0;
    for (int j = 0; j < n; ++j) {
        double sj = sdyn[j];
        rank += (int)((sj > st) || (sj == st && j < t));
    }
    if (rank < k) {
        int p = b * k + rank;
        nodemap[gid] = p;
        perm_int[p] = gid;
        out[off_batch + p] = (float)b;
        out[off_perm + p]  = (float)gid;
    } else {
        nodemap[gid] = -1;
    }
}

__global__ void gather_kernel(const float* __restrict__ x,
                              const double* __restrict__ scores,
                              const int* __restrict__ perm_int,
                              float* __restrict__ out0, int D) {
    int p = blockIdx.x;
    int l = threadIdx.x;
    int gid = perm_int[p];
    double sc = scores[gid];
    float g = (float)(1.0 / (1.0 + exp(-sc)));
    const float* xr = x + (size_t)gid * D;
    float* orow = out0 + (size_t)p * D;
    for (int j = l; j < D; j += 64) orow[j] = xr[j] * g;
}

__global__ void edge_kernel(const int* __restrict__ ei,
                            const int* __restrict__ nodemap,
                            float* __restrict__ out,
                            long off_e, long off_valid, long E) {
    long e = (long)blockIdx.x * blockDim.x + threadIdx.x;
    if (e >= E) return;
    int r = nodemap[ei[e]];
    int c = nodemap[ei[E + e]];
    bool valid = (r >= 0) && (c >= 0);
    out[off_e + e]     = valid ? (float)r : -1.0f;
    out[off_e + E + e] = valid ? (float)c : -1.0f;
    out[off_valid + e] = valid ? 1.0f : 0.0f;
}

// ============================================================================
extern "C" void kernel_launch(void* const* d_in, const int* in_sizes, int n_in,
                              void* d_out, int out_size, void* d_ws, size_t ws_size,
                              hipStream_t stream) {
    const float* x    = (const float*)d_in[0];
    const int*   ei   = (const int*)d_in[1];
    const float* pool = (const float*)d_in[3];

    const int B = in_sizes[4];
    const int D = in_sizes[3] / B;
    const long N = (long)in_sizes[0] / D;
    const long E = (long)in_sizes[1] / 2;
    const int n = (int)(N / B);
    const int k = (n + 1) / 2;            // ceil(0.5 * n)
    const long Eg = E / B;                // edges per graph

    // workspace layout
    char* ws = (char*)d_ws;
    double* scores   = (double*)ws;                 ws += (size_t)N * 8;
    double* inv_norm = (double*)ws;                 ws += (size_t)B * 8;
    int*    nodemap  = (int*)ws;                    ws += (size_t)N * 4;
    int*    perm_int = (int*)ws;

    float* out = (float*)d_out;
    const long o0 = 0;                       // x_out [B*k, D]
    const long o1 = o0 + (long)B * k * D;    // edge_index_new [2, E]
    const long o2 = o1 + 2 * E;              // batch_out [B*k]
    const long o3 = o2 + (long)B * k;        // perm [B*k]
    const long o4 = o3 + (long)B * k;        // valid [E]

    bool fast_ok = (D == 256) && (n % 64 == 0) && (n <= 1024) && (k % 64 == 0) &&
                   (E % 2048 == 0) && (Eg % 2048 == 0) &&
                   (o1 % 4 == 0) && ((o1 + E) % 4 == 0) && (o4 % 4 == 0);

    if (fast_ok) {
        srg_kernel<<<B, 1024, 0, stream>>>(
            (const float4*)x, (const float4*)pool, nodemap,
            (float4*)(out + o0), out + o2, out + o3, n, k);
        edge_out_kernel<<<(int)(E / 2048), 256, 0, stream>>>(
            (const int4*)ei, (const int4*)(ei + E), nodemap,
            (float4*)(out + o1), (float4*)(out + o1 + E), (float4*)(out + o4),
            Eg / 4, n);
    } else {
        norm_kernel<<<B, 64, 0, stream>>>(pool, inv_norm, D);
        score_kernel<<<(int)(N / 4), 256, 0, stream>>>(
            x, pool, inv_norm, scores, D, n);
        rank_kernel<<<B, n, (size_t)n * sizeof(double), stream>>>(
            scores, nodemap, perm_int, out, o2, o3, n, k);
        gather_kernel<<<(int)((long)B * k), 64, 0, stream>>>(
            x, scores, perm_int, out + o0, D);
        edge_kernel<<<(int)((E + 255) / 256), 256, 0, stream>>>(
            ei, nodemap, out, o1, o4, E);
    }
}